// Round 4
// baseline (230.965 us; speedup 1.0000x reference)
//
#include <hip/hip_runtime.h>
#include <hip/hip_bf16.h>
#include <stdint.h>

typedef __bf16 bf16x8 __attribute__((ext_vector_type(8)));
typedef float  f32x4  __attribute__((ext_vector_type(4)));
typedef float  f32x2  __attribute__((ext_vector_type(2)));

#define N_NODES 100000
#define DIM     128
#define B_BATCH 20000
#define K_NB    32
#define O_OUT   128

// ---------------- K0: transpose + bf16 convert weights ----------------
// W1 (128x128, [k][c]) -> W1t[c][k] bf16 ; Wn (256x128, [k][o]) -> Wnt[o][k] bf16
__global__ void transpose_weights(const float* __restrict__ W1,
                                  const float* __restrict__ Wn,
                                  __bf16* __restrict__ W1t,
                                  __bf16* __restrict__ Wnt) {
    int tid = blockIdx.x * blockDim.x + threadIdx.x;
    if (tid < DIM * DIM) {
        int k = tid >> 7, c = tid & 127;
        W1t[c * DIM + k] = (__bf16)W1[tid];
    }
    int t2 = tid - DIM * DIM;
    if (t2 >= 0 && t2 < 2 * DIM * O_OUT) {
        int k = t2 >> 7, o = t2 & 127;
        Wnt[o * (2 * DIM) + k] = (__bf16)Wn[t2];
    }
}

// ---------------- K1: H = relu(features @ W1 + b1), bf16 out ----------------
// 64 rows/block, 4 waves, each wave: 16 rows x 128 cols (8 MFMA col-tiles).
// A fragments loaded straight from global (coalesced 16B), B from L2-hot W1t.
__global__ __launch_bounds__(256, 4)
void gemm_h(const float* __restrict__ X, const __bf16* __restrict__ W1t,
            const float* __restrict__ b1, __bf16* __restrict__ H) {
    const int lane = threadIdx.x & 63;
    const int wave = threadIdx.x >> 6;
    const int rowbase = blockIdx.x * 64 + wave * 16;
    const int r0 = lane & 15;
    const int kg = lane >> 4;          // 0..3
    int arow = rowbase + r0;
    int arow_c = arow < N_NODES ? arow : 0;

    f32x4 acc[8];
#pragma unroll
    for (int t = 0; t < 8; ++t) acc[t] = (f32x4)0.0f;

#pragma unroll
    for (int k0 = 0; k0 < DIM; k0 += 32) {
        const int k = k0 + kg * 8;
        const float* ap = X + arow_c * DIM + k;
        f32x4 a0 = *(const f32x4*)ap;
        f32x4 a1 = *(const f32x4*)(ap + 4);
        bf16x8 af;
        af[0]=(__bf16)a0[0]; af[1]=(__bf16)a0[1]; af[2]=(__bf16)a0[2]; af[3]=(__bf16)a0[3];
        af[4]=(__bf16)a1[0]; af[5]=(__bf16)a1[1]; af[6]=(__bf16)a1[2]; af[7]=(__bf16)a1[3];
#pragma unroll
        for (int ct = 0; ct < 8; ++ct) {
            const int col = ct * 16 + r0;
            bf16x8 bf = *(const bf16x8*)(W1t + col * DIM + k);
            acc[ct] = __builtin_amdgcn_mfma_f32_16x16x32_bf16(af, bf, acc[ct], 0, 0, 0);
        }
    }
    // D layout: col = lane&15, row = (lane>>4)*4 + reg   [m89-verified mapping]
    const int orow_base = rowbase + kg * 4;
#pragma unroll
    for (int ct = 0; ct < 8; ++ct) {
        const int col = ct * 16 + r0;
        const float bias = b1[col];
#pragma unroll
        for (int r = 0; r < 4; ++r) {
            const int row = orow_base + r;
            if (row < N_NODES) {
                float v = acc[ct][r] + bias;
                H[row * DIM + col] = (__bf16)(v > 0.f ? v : 0.f);
            }
        }
    }
}

// ---------------- K2a: pooled mean over gathered H rows + concat node feat ----
// 1 wave per b; lane owns 2 columns. H is 25.6MB -> L3 resident.
__global__ __launch_bounds__(256)
void pool_concat(const __bf16* __restrict__ H, const float* __restrict__ X,
                 const int* __restrict__ node, const int* __restrict__ nb,
                 __bf16* __restrict__ Cc) {
    const int lane = threadIdx.x & 63;
    const int wave = threadIdx.x >> 6;
    const int b = blockIdx.x * 4 + wave;

    // node feature -> first 128 cols (bf16)
    const int ni = node[b];
    f32x2 nf = *(const f32x2*)(X + (long)ni * DIM + lane * 2);
    union { __bf16 h[2]; uint32_t u; } pk;
    __bf16* crow = Cc + (long)b * 256;
    pk.h[0] = (__bf16)nf[0]; pk.h[1] = (__bf16)nf[1];
    *(uint32_t*)(crow + lane * 2) = pk.u;

    float s0 = 0.f, s1 = 0.f;
    const int* nbp = nb + b * K_NB;
#pragma unroll
    for (int k = 0; k < K_NB; ++k) {
        const int idx = nbp[k];
        uint32_t u = *(const uint32_t*)(H + (long)idx * DIM + lane * 2);
        s0 += __uint_as_float(u << 16);
        s1 += __uint_as_float(u & 0xffff0000u);
    }
    pk.h[0] = (__bf16)(s0 * (1.0f / K_NB));
    pk.h[1] = (__bf16)(s1 * (1.0f / K_NB));
    *(uint32_t*)(crow + 128 + lane * 2) = pk.u;
}

// ---------------- K2b: out = relu(Cc @ Wn), f32 out ----------------
__global__ __launch_bounds__(256, 4)
void gemm_out(const __bf16* __restrict__ Cc, const __bf16* __restrict__ Wnt,
              float* __restrict__ Out) {
    const int lane = threadIdx.x & 63;
    const int wave = threadIdx.x >> 6;
    const int rowbase = blockIdx.x * 64 + wave * 16;
    const int r0 = lane & 15;
    const int kg = lane >> 4;
    int arow = rowbase + r0;
    int arow_c = arow < B_BATCH ? arow : 0;

    f32x4 acc[8];
#pragma unroll
    for (int t = 0; t < 8; ++t) acc[t] = (f32x4)0.0f;

#pragma unroll
    for (int k0 = 0; k0 < 2 * DIM; k0 += 32) {
        const int k = k0 + kg * 8;
        bf16x8 af = *(const bf16x8*)(Cc + (long)arow_c * 256 + k);
#pragma unroll
        for (int ct = 0; ct < 8; ++ct) {
            const int col = ct * 16 + r0;
            bf16x8 bf = *(const bf16x8*)(Wnt + col * 256 + k);
            acc[ct] = __builtin_amdgcn_mfma_f32_16x16x32_bf16(af, bf, acc[ct], 0, 0, 0);
        }
    }
    const int orow_base = rowbase + kg * 4;
#pragma unroll
    for (int ct = 0; ct < 8; ++ct) {
        const int col = ct * 16 + r0;
#pragma unroll
        for (int r = 0; r < 4; ++r) {
            const int row = orow_base + r;
            if (row < B_BATCH) {
                float v = acc[ct][r];
                Out[(long)row * O_OUT + col] = v > 0.f ? v : 0.f;
            }
        }
    }
}

// ---------------- K3: raw_features passthrough copy ----------------
__global__ __launch_bounds__(256)
void copy_raw(const float4* __restrict__ src, float4* __restrict__ dst, int n4) {
    int i = blockIdx.x * blockDim.x + threadIdx.x;
    const int stride = gridDim.x * blockDim.x;
    for (; i < n4; i += stride) dst[i] = src[i];
}

extern "C" void kernel_launch(void* const* d_in, const int* in_sizes, int n_in,
                              void* d_out, int out_size, void* d_ws, size_t ws_size,
                              hipStream_t stream) {
    const float* features = (const float*)d_in[0];
    const float* raw      = (const float*)d_in[1];
    const float* W1       = (const float*)d_in[2];
    const float* b1       = (const float*)d_in[3];
    const float* Wn       = (const float*)d_in[4];
    const int*   node     = (const int*)d_in[5];
    const int*   nb       = (const int*)d_in[6];
    float* out = (float*)d_out;

    // workspace layout (35.94 MB total)
    char* ws = (char*)d_ws;
    __bf16* H   = (__bf16*)ws;                          // 100000*128*2 = 25,600,000 B
    __bf16* W1t = (__bf16*)(ws + 25600000);             // 32,768 B
    __bf16* Wnt = (__bf16*)(ws + 25632768);             // 65,536 B
    __bf16* Cc  = (__bf16*)(ws + 25698304);             // 20000*256*2 = 10,240,000 B

    transpose_weights<<<(DIM*DIM + 2*DIM*O_OUT) / 256, 256, 0, stream>>>(W1, Wn, W1t, Wnt);
    gemm_h<<<(N_NODES + 63) / 64, 256, 0, stream>>>(features, W1t, b1, H);
    pool_concat<<<B_BATCH / 4, 256, 0, stream>>>(H, features, node, nb, Cc);
    gemm_out<<<(B_BATCH + 63) / 64, 256, 0, stream>>>(Cc, Wnt, out);
    copy_raw<<<2048, 256, 0, stream>>>((const float4*)raw,
                                       (float4*)(out + (long)B_BATCH * O_OUT),
                                       N_NODES * DIM / 4);
}